// Round 5
// baseline (322.712 us; speedup 1.0000x reference)
//
#include <hip/hip_runtime.h>
#include <math.h>

// NetVLAD fused. R5: depth-2 register prefetch in both GEMMs (loads stay in
// flight across 2 barrier phases); k_agg full-N per block with direct stores
// (no atomics, no out zeroing). Split-bf16 (hi+lo) 3-pass MFMA numerics
// unchanged from R4 (absmax 6.1e-5 == fp32 baseline).
// B=32, D=512, N=2048, K=64.

typedef __attribute__((ext_vector_type(8))) short bf16x8;
typedef __attribute__((ext_vector_type(4))) float f32x4;

namespace {
constexpr int Bv = 32;
constexpr int Dv = 512;
constexpr int Nv = 2048;
constexpr int Kv = 64;
constexpr float EPSv = 1e-12f;
}

union Frag {
  uint4 q;
  bf16x8 v;
};

// truncation split: hi = top16(v) (exact bf16), lo = bf16(v - hi)
__device__ __forceinline__ unsigned pack2bf(float a, float b) {
  return (__float_as_uint(a) >> 16) | (__float_as_uint(b) & 0xFFFF0000u);
}
__device__ __forceinline__ float hi_f32(float a) {
  return __uint_as_float(__float_as_uint(a) & 0xFFFF0000u);
}
__device__ __forceinline__ void split4(const float4& f, uint2& h, uint2& l) {
  h.x = pack2bf(f.x, f.y);
  h.y = pack2bf(f.z, f.w);
  l.x = pack2bf(f.x - hi_f32(f.x), f.y - hi_f32(f.y));
  l.y = pack2bf(f.z - hi_f32(f.z), f.w - hi_f32(f.w));
}

// ---------------------------------------------------------------------------
// Prep: W -> Whi/Wlo bf16; zero s_sum + colsq. Grid 128 blocks.
// ---------------------------------------------------------------------------
__global__ __launch_bounds__(256) void k_prep(const float* __restrict__ W,
                                              float* __restrict__ aux,
                                              unsigned short* __restrict__ Whi,
                                              unsigned short* __restrict__ Wlo) {
  const int i = blockIdx.x * 256 + threadIdx.x;
  if (i < Kv * Dv) {
    const float w = W[i];
    Whi[i] = (unsigned short)(__float_as_uint(w) >> 16);
    Wlo[i] = (unsigned short)(__float_as_uint(w - hi_f32(w)) >> 16);
  }
  if (i < 2 * Bv * Kv) aux[i] = 0.f;
}

// ---------------------------------------------------------------------------
// K1: scores = W·x[b], softmax over k, p fp32 via LDS transpose, s_sum atomics.
// Block 256 thr / 4 waves; 64k x 64n tile; 16 d-steps of 32.
// Depth-2 register prefetch: reg sets A/B, loop unrolled x2; LWRITE always
// writes loads issued one full iteration earlier (no vmcnt drain stall).
// LDS 37.9KB -> 4 blocks/CU. Grid (32, 32).
// ---------------------------------------------------------------------------
__global__ __launch_bounds__(256) void k_scores(const float* __restrict__ x,
                                                const unsigned short* __restrict__ Whi,
                                                const unsigned short* __restrict__ Wlo,
                                                float* __restrict__ p,
                                                float* __restrict__ s_sum) {
  const int b = blockIdx.y;
  const int n0 = blockIdx.x * 64;
  const int tid = threadIdx.x;
  const int lane = tid & 63;
  const int wv = tid >> 6;
  const int r = lane & 15;
  const int g = lane >> 4;

  __shared__ __align__(16) unsigned short wlds[2][2][64][40];  // [buf][hi/lo][k][d]
  __shared__ __align__(16) float xlds[2][32][68];              // [buf][d][n]
  float* plds = &xlds[0][0][0];  // aliased after K-loop: [64][68]

  const float* xb = x + (size_t)b * Dv * Nv;

  f32x4 acc[4];
#pragma unroll
  for (int mb = 0; mb < 4; ++mb) acc[mb] = (f32x4){0.f, 0.f, 0.f, 0.f};

  const int wk = tid >> 2;   // W row 0..63
  const int wdg = tid & 3;   // W 16B group
  const int xd = tid >> 3;   // x d-row 0..31
  const int xng = tid & 7;   // x n-group

  uint4 rwhA, rwlA, rwhB, rwlB;
  float4 rxaA, rxbA, rxaB, rxbB;

#define GLOAD(S, rwh, rwl, rxa, rxb)                                      \
  do {                                                                    \
    rwh = *(const uint4*)&Whi[wk * Dv + (S) * 32 + wdg * 8];              \
    rwl = *(const uint4*)&Wlo[wk * Dv + (S) * 32 + wdg * 8];              \
    const float* src = &xb[(size_t)((S) * 32 + xd) * Nv + n0 + xng * 8];  \
    rxa = *(const float4*)src;                                            \
    rxb = *(const float4*)(src + 4);                                      \
  } while (0)

#define LWRITE(buf, rwh, rwl, rxa, rxb)               \
  do {                                                \
    *(uint4*)&wlds[buf][0][wk][wdg * 8] = rwh;        \
    *(uint4*)&wlds[buf][1][wk][wdg * 8] = rwl;        \
    *(float4*)&xlds[buf][xd][xng * 8] = rxa;          \
    *(float4*)&xlds[buf][xd][xng * 8 + 4] = rxb;      \
  } while (0)

#define COMPUTE(buf)                                                          \
  do {                                                                        \
    float xf[8];                                                              \
    _Pragma("unroll") for (int j = 0; j < 8; ++j)                             \
        xf[j] = xlds[buf][g * 8 + j][wv * 16 + r];                            \
    Frag bh, bl;                                                              \
    _Pragma("unroll") for (int j = 0; j < 4; ++j) {                           \
      const float e = xf[2 * j], o = xf[2 * j + 1];                           \
      ((unsigned*)&bh.q)[j] = pack2bf(e, o);                                  \
      ((unsigned*)&bl.q)[j] = pack2bf(e - hi_f32(e), o - hi_f32(o));          \
    }                                                                         \
    _Pragma("unroll") for (int mb = 0; mb < 4; ++mb) {                        \
      Frag ah, al;                                                            \
      ah.q = *(const uint4*)&wlds[buf][0][mb * 16 + r][g * 8];                \
      al.q = *(const uint4*)&wlds[buf][1][mb * 16 + r][g * 8];                \
      acc[mb] = __builtin_amdgcn_mfma_f32_16x16x32_bf16(ah.v, bh.v, acc[mb], 0, 0, 0); \
      acc[mb] = __builtin_amdgcn_mfma_f32_16x16x32_bf16(ah.v, bl.v, acc[mb], 0, 0, 0); \
      acc[mb] = __builtin_amdgcn_mfma_f32_16x16x32_bf16(al.v, bh.v, acc[mb], 0, 0, 0); \
    }                                                                         \
  } while (0)

  // Prologue: 2 steps in flight; write step 0.
  GLOAD(0, rwhA, rwlA, rxaA, rxbA);
  GLOAD(1, rwhB, rwlB, rxaB, rxbB);
  LWRITE(0, rwhA, rwlA, rxaA, rxbA);
  __syncthreads();

  for (int s = 0; s < 16; s += 2) {
    // even phase: compute buf0 (step s); write buf1 (step s+1, loaded >=1 iter ago)
    if (s + 2 < 16) GLOAD(s + 2, rwhA, rwlA, rxaA, rxbA);
    COMPUTE(0);
    LWRITE(1, rwhB, rwlB, rxaB, rxbB);
    __syncthreads();
    // odd phase: compute buf1 (step s+1); write buf0 (step s+2)
    if (s + 3 < 16) GLOAD(s + 3, rwhB, rwlB, rxaB, rxbB);
    COMPUTE(1);
    if (s + 2 < 16) LWRITE(0, rwhA, rwlA, rxaA, rxbA);
    __syncthreads();
  }
#undef GLOAD
#undef LWRITE
#undef COMPUTE

  // ---- softmax over k (lane holds 16 k for one n; cross-lane over lane>>4) ----
  float v[16];
#pragma unroll
  for (int mb = 0; mb < 4; ++mb)
#pragma unroll
    for (int q = 0; q < 4; ++q) v[mb * 4 + q] = acc[mb][q];

  float m = v[0];
#pragma unroll
  for (int i = 1; i < 16; ++i) m = fmaxf(m, v[i]);
  m = fmaxf(m, __shfl_xor(m, 16));
  m = fmaxf(m, __shfl_xor(m, 32));

  float sm = 0.f;
#pragma unroll
  for (int i = 0; i < 16; ++i) {
    v[i] = __expf(v[i] - m);
    sm += v[i];
  }
  sm += __shfl_xor(sm, 16);
  sm += __shfl_xor(sm, 32);
  const float rs = 1.f / sm;

  // transpose through LDS: plds[k][n-local], stride 68
  const int nl = wv * 16 + r;
#pragma unroll
  for (int mb = 0; mb < 4; ++mb)
#pragma unroll
    for (int q = 0; q < 4; ++q)
      plds[(mb * 16 + g * 4 + q) * 68 + nl] = v[mb * 4 + q] * rs;
  __syncthreads();

  // coalesced p store + s_sum partial
  const int pk = tid >> 2;
  const int png = tid & 3;
  const float4 p0 = *(const float4*)&plds[pk * 68 + png * 16];
  const float4 p1 = *(const float4*)&plds[pk * 68 + png * 16 + 4];
  const float4 p2 = *(const float4*)&plds[pk * 68 + png * 16 + 8];
  const float4 p3 = *(const float4*)&plds[pk * 68 + png * 16 + 12];
  const float part = (p0.x + p0.y + p0.z + p0.w) + (p1.x + p1.y + p1.z + p1.w) +
                     (p2.x + p2.y + p2.z + p2.w) + (p3.x + p3.y + p3.z + p3.w);
  atomicAdd(&s_sum[b * Kv + pk], part);
  float* dst = &p[((size_t)b * Kv + pk) * Nv + n0 + png * 16];
  *(float4*)dst = p0;
  *(float4*)(dst + 4) = p1;
  *(float4*)(dst + 8) = p2;
  *(float4*)(dst + 12) = p3;
}

// ---------------------------------------------------------------------------
// K2: agg[b,d,k] = sum_n x*p via MFMA, full N per block -> direct store.
// Block 512 thr / 8 waves (wd 0..1 x wk 0..3): 64d x 64k tile, 64 n-steps
// of 32. Depth-2 register prefetch; split-bf16 at stage. Grid (8, 32).
// LDS 40KB. Epilogue: out = agg (no atomics); centers handled in k_norm.
// ---------------------------------------------------------------------------
__global__ __launch_bounds__(512) void k_agg(const float* __restrict__ x,
                                             const float* __restrict__ p,
                                             float* __restrict__ out) {
  const int d_base = blockIdx.x * 64;
  const int b = blockIdx.y;
  const int tid = threadIdx.x;
  const int lane = tid & 63;
  const int wv = tid >> 6;
  const int wd = wv >> 2;   // 0..1 -> 32 d
  const int wk = wv & 3;    // 0..3 -> 16 k
  const int r = lane & 15;
  const int g = lane >> 4;

  __shared__ __align__(16) unsigned short xt[2][2][64][40];  // [buf][hi/lo][d][n]
  __shared__ __align__(16) unsigned short pt[2][2][64][40];  // [buf][hi/lo][k][n]

  const float* xb = x + (size_t)b * Dv * Nv;
  const float* pb = p + (size_t)b * Kv * Nv;

  f32x4 acc[2];
#pragma unroll
  for (int mb = 0; mb < 2; ++mb) acc[mb] = (f32x4){0.f, 0.f, 0.f, 0.f};

  const int sr = tid >> 3;  // row 0..63 (d for x, k for p)
  const int sg = tid & 7;   // 4-float group (32 n per step)

  float4 rxA, rpA, rxB, rpB;

#define GLOADA(S, rx, rp)                                                 \
  do {                                                                    \
    rx = *(const float4*)&xb[(size_t)(d_base + sr) * Nv + (S) * 32 + sg * 4]; \
    rp = *(const float4*)&pb[(size_t)sr * Nv + (S) * 32 + sg * 4];        \
  } while (0)

#define LWRITEA(buf, rx, rp)                          \
  do {                                                \
    uint2 h, l;                                       \
    split4(rx, h, l);                                 \
    *(uint2*)&xt[buf][0][sr][sg * 4] = h;             \
    *(uint2*)&xt[buf][1][sr][sg * 4] = l;             \
    split4(rp, h, l);                                 \
    *(uint2*)&pt[buf][0][sr][sg * 4] = h;             \
    *(uint2*)&pt[buf][1][sr][sg * 4] = l;             \
  } while (0)

#define COMPUTEA(buf)                                                         \
  do {                                                                        \
    Frag xh[2], xl[2], ph, pl;                                                \
    _Pragma("unroll") for (int mb = 0; mb < 2; ++mb) {                        \
      xh[mb].q = *(const uint4*)&xt[buf][0][wd * 32 + mb * 16 + r][g * 8];    \
      xl[mb].q = *(const uint4*)&xt[buf][1][wd * 32 + mb * 16 + r][g * 8];    \
    }                                                                         \
    ph.q = *(const uint4*)&pt[buf][0][wk * 16 + r][g * 8];                    \
    pl.q = *(const uint4*)&pt[buf][1][wk * 16 + r][g * 8];                    \
    _Pragma("unroll") for (int mb = 0; mb < 2; ++mb) {                        \
      acc[mb] = __builtin_amdgcn_mfma_f32_16x16x32_bf16(xh[mb].v, ph.v, acc[mb], 0, 0, 0); \
      acc[mb] = __builtin_amdgcn_mfma_f32_16x16x32_bf16(xh[mb].v, pl.v, acc[mb], 0, 0, 0); \
      acc[mb] = __builtin_amdgcn_mfma_f32_16x16x32_bf16(xl[mb].v, ph.v, acc[mb], 0, 0, 0); \
    }                                                                         \
  } while (0)

  GLOADA(0, rxA, rpA);
  GLOADA(1, rxB, rpB);
  LWRITEA(0, rxA, rpA);
  __syncthreads();

  const int STEPS = Nv / 32;  // 64
  for (int s = 0; s < STEPS; s += 2) {
    if (s + 2 < STEPS) GLOADA(s + 2, rxA, rpA);
    COMPUTEA(0);
    LWRITEA(1, rxB, rpB);
    __syncthreads();
    if (s + 3 < STEPS) GLOADA(s + 3, rxB, rpB);
    COMPUTEA(1);
    if (s + 2 < STEPS) LWRITEA(0, rxA, rpA);
    __syncthreads();
  }
#undef GLOADA
#undef LWRITEA
#undef COMPUTEA

  // Direct store (full N reduced in-block; no atomics).
#pragma unroll
  for (int mb = 0; mb < 2; ++mb) {
#pragma unroll
    for (int q = 0; q < 4; ++q) {
      const int d = d_base + wd * 32 + mb * 16 + g * 4 + q;
      const int k = wk * 16 + r;
      out[((size_t)b * Dv + d) * Kv + k] = acc[mb][q];
    }
  }
}

// ---------------------------------------------------------------------------
// K3a: column sumsq of desc = out - centers*s_sum -> colsq atomics.
// ---------------------------------------------------------------------------
__global__ __launch_bounds__(256) void k_norm1(const float* __restrict__ out,
                                               const float* __restrict__ centers,
                                               const float* __restrict__ s_sum,
                                               float* __restrict__ colsq) {
  const int b = blockIdx.y;
  const int d0 = blockIdx.x * 64;
  const int k = threadIdx.x & 63;
  const int dq = threadIdx.x >> 6;

  __shared__ float red[4][64];

  const float sv = s_sum[b * Kv + k];
  float ssq = 0.f;
#pragma unroll
  for (int i = 0; i < 16; ++i) {
    const int d = d0 + dq * 16 + i;
    const float a = out[((size_t)b * Dv + d) * Kv + k];
    const float v = fmaf(-centers[d * Kv + k], sv, a);
    ssq = fmaf(v, v, ssq);
  }
  red[dq][k] = ssq;
  __syncthreads();
  if (threadIdx.x < 64) {
    const int kk = threadIdx.x;
    atomicAdd(&colsq[b * Kv + kk],
              red[0][kk] + red[1][kk] + red[2][kk] + red[3][kk]);
  }
}

// ---------------------------------------------------------------------------
// K3b: final scale: out = (out - centers*s_sum) * rn[k] * rtot.
// ---------------------------------------------------------------------------
__global__ __launch_bounds__(256) void k_norm2(float* __restrict__ out,
                                               const float* __restrict__ centers,
                                               const float* __restrict__ s_sum,
                                               const float* __restrict__ colsq) {
  const int b = blockIdx.y;
  const int d0 = blockIdx.x * 64;
  const int k = threadIdx.x & 63;
  const int dq = threadIdx.x >> 6;

  __shared__ float rns[64];
  __shared__ float red2[64];
  __shared__ float rtot_s;

  if (threadIdx.x < 64) {
    const float t = colsq[b * Kv + threadIdx.x];
    const float rn = 1.f / fmaxf(sqrtf(t), EPSv);
    rns[threadIdx.x] = rn;
    red2[threadIdx.x] = t * rn * rn;
  }
  __syncthreads();
  if (threadIdx.x == 0) {
    float t = 0.f;
#pragma unroll
    for (int kk = 0; kk < 64; ++kk) t += red2[kk];
    rtot_s = 1.f / fmaxf(sqrtf(t), EPSv);
  }
  __syncthreads();

  const float scale = rns[k] * rtot_s;
  const float sv = s_sum[b * Kv + k];
#pragma unroll
  for (int i = 0; i < 16; ++i) {
    const int d = d0 + dq * 16 + i;
    const size_t idx = ((size_t)b * Dv + d) * Kv + k;
    const float v = fmaf(-centers[d * Kv + k], sv, out[idx]);
    out[idx] = v * scale;
  }
}

// ---------------------------------------------------------------------------
extern "C" void kernel_launch(void* const* d_in, const int* in_sizes, int n_in,
                              void* d_out, int out_size, void* d_ws, size_t ws_size,
                              hipStream_t stream) {
  (void)in_sizes; (void)n_in; (void)out_size; (void)ws_size;
  const float* x = (const float*)d_in[0];        // [B, D, N]
  const float* W = (const float*)d_in[1];        // [K, D]
  const float* centers = (const float*)d_in[2];  // [D, K]
  float* out = (float*)d_out;                    // [B, D*K]

  // ws: p fp32 [B*K*N], s_sum [B*K], colsq [B*K], Whi/Wlo bf16 [K*D]
  float* p = (float*)d_ws;
  float* s_sum = p + (size_t)Bv * Kv * Nv;
  float* colsq = s_sum + Bv * Kv;
  unsigned short* Whi = (unsigned short*)(colsq + Bv * Kv);
  unsigned short* Wlo = Whi + Kv * Dv;

  k_prep<<<dim3((Kv * Dv + 255) / 256), 256, 0, stream>>>(W, s_sum, Whi, Wlo);
  k_scores<<<dim3(Nv / 64, Bv), 256, 0, stream>>>(x, Whi, Wlo, p, s_sum);
  k_agg<<<dim3(Dv / 64, Bv), 512, 0, stream>>>(x, p, out);
  k_norm1<<<dim3(Dv / 64, Bv), 256, 0, stream>>>(out, centers, s_sum, colsq);
  k_norm2<<<dim3(Dv / 64, Bv), 256, 0, stream>>>(out, centers, s_sum, colsq);
}